// Round 1
// baseline (1152.096 us; speedup 1.0000x reference)
//
#include <hip/hip_runtime.h>

namespace {
constexpr int D = 4096;   // d_model
constexpr int E = 64;     // n_experts
constexpr int M = 16384;  // B*S
constexpr int BM = 64;    // rows per block
constexpr int BK = 128;   // k per round
constexpr int NT = D / BK;      // 32 rounds
constexpr int NBLK = M / BM;    // 256 blocks

// output layout (floats, concatenated in reference return order)
constexpr int OFF_IDX = 0;         // [M][2]
constexpr int OFF_SCORES = 32768;  // [M][2]
constexpr int OFF_PROBS = 65536;   // [M][64]
constexpr int OFF_Z = 1114112;     // scalar
constexpr int OFF_IMP = 1114113;   // [64]
constexpr int OFF_LOAD = 1114177;  // [64]

constexpr int WS_STRIDE = 132;  // per-block stats: 64 imp | 64 cnt | 1 z2
}  // namespace

// ---------------------------------------------------------------------------
// Fused router. 256 blocks x 512 threads (8 waves = 8 wave-aligned k-slices).
// LDS 128 KB: double-buffered k-major tiles Xs[k][64], Ws[k][64], rows XOR-
// swizzled by (k>>2)&7 so staging writes hit all 32 banks (2-way = free) and
// fragment reads stay broadcast/2-way. 8x8 register tile per thread.
// Cross-slice reduction + top2/softmax epilogue are fully wave-parallel.
// ---------------------------------------------------------------------------
__global__ __launch_bounds__(512, 2) void router_fused(
    const float* __restrict__ xg, const float* __restrict__ wg,
    float* __restrict__ out, float* __restrict__ ws) {
  __shared__ float smem[32768];  // 128 KB = 2 buffers x (Xs 8192 | Ws 8192)

  const int t = threadIdx.x;
  const int u = t & 63;   // lane
  const int s = t >> 6;   // wave id = k-slice 0..7 (16 k each per round)
  const int tx = u & 7;   // expert group (8 experts)
  const int ty = u >> 3;  // row group (8 rows)
  const int r0 = blockIdx.x * BM;

  // staging: thread covers row sr, k-cols sc + {0,32,64,96}
  const int sr = t >> 3;       // 0..63
  const int sc = (t & 7) * 4;  // 0..28
  const float* xp = xg + (size_t)(r0 + sr) * D + sc;
  const float* wp = wg + (size_t)sr * D + sc;
  // swizzle row' = row ^ ((k>>2 & 7)<<2); for this thread (k>>2)&7 == t&7
  const int rp = sr ^ ((t & 7) << 2);

  float4 vx[4], vw[4];
  auto stage_load = [&](int k0) {
#pragma unroll
    for (int h = 0; h < 4; ++h) {
      vx[h] = *(const float4*)(xp + k0 + h * 32);
      vw[h] = *(const float4*)(wp + k0 + h * 32);
    }
  };
  auto stage_write = [&](float* buf) {
#pragma unroll
    for (int h = 0; h < 4; ++h) {
      float* px = buf + (sc + h * 32) * 64 + rp;  // element (c+q) at px[q*64]
      px[0] = vx[h].x; px[64] = vx[h].y; px[128] = vx[h].z; px[192] = vx[h].w;
      float* pw = px + 8192;
      pw[0] = vw[h].x; pw[64] = vw[h].y; pw[128] = vw[h].z; pw[192] = vw[h].w;
    }
  };

  float acc[8][8];
#pragma unroll
  for (int i = 0; i < 8; ++i)
#pragma unroll
    for (int j = 0; j < 8; ++j) acc[i][j] = 0.f;

  // read-side swizzle bases: vb(k) = ((k>>2)&7)<<2 = ((s&1)<<4) | ((kk>>2)<<2)
  const int rxs = (ty * 8) ^ ((s & 1) << 4);
  const int rws = (tx * 8) ^ ((s & 1) << 4);

  stage_load(0);
  stage_write(smem);  // buffer 0

  for (int r = 0; r < NT; ++r) {
    __syncthreads();  // tile r ready; all waves done with tile r-1's buffer
    if (r + 1 < NT) stage_load((r + 1) * BK);  // global loads fly over compute

    const float* buf = smem + (r & 1) * 16384;
    const float* Xs = buf + s * 1024;         // slice base (k = s*16 + kk)
    const float* Ws = buf + 8192 + s * 1024;
#pragma unroll
    for (int kk = 0; kk < 16; ++kk) {
      const int vb = (kk >> 2) << 2;  // compile-time per iteration
      const int px = rxs ^ vb;
      const int pw = rws ^ vb;
      // first b128 -> rows +0..3, second (at pos^4) -> rows +4..7
      const float4 a0 = *(const float4*)&Xs[kk * 64 + px];
      const float4 a1 = *(const float4*)&Xs[kk * 64 + (px ^ 4)];
      const float4 b0 = *(const float4*)&Ws[kk * 64 + pw];
      const float4 b1 = *(const float4*)&Ws[kk * 64 + (pw ^ 4)];
      const float av[8] = {a0.x, a0.y, a0.z, a0.w, a1.x, a1.y, a1.z, a1.w};
      const float bv[8] = {b0.x, b0.y, b0.z, b0.w, b1.x, b1.y, b1.z, b1.w};
#pragma unroll
      for (int i = 0; i < 8; ++i)
#pragma unroll
        for (int j = 0; j < 8; ++j) acc[i][j] = fmaf(av[i], bv[j], acc[i][j]);
    }
    if (r + 1 < NT) stage_write(smem + ((r + 1) & 1) * 16384);  // other buffer
  }

  // ---- cross-slice reduction, distributed over all 512 threads ----
  // P[jp][slice*64+u][2] float2 layout: both sides bank-optimal.
  // acc[i][j] of thread (s,u) is logits(row=(u>>3)*8+i, e=(u&7)*8+j).
  __syncthreads();  // all compute done; gemm buffers reusable
  {
    float* P = smem;
    const int su2 = (s * 64 + u) * 2;
#pragma unroll
    for (int i = 0; i < 8; ++i)
#pragma unroll
      for (int jj = 0; jj < 4; ++jj)
        *(float2*)&P[(i * 4 + jj) * 1024 + su2] =
            make_float2(acc[i][2 * jj], acc[i][2 * jj + 1]);
  }
  __syncthreads();

  // thread t = (s,u) gathers row (u>>3)*8 + s, experts (u&7)*8 + 0..7
  float v[8];
#pragma unroll
  for (int q = 0; q < 8; ++q) v[q] = 0.f;
  {
    const float* P = smem;
#pragma unroll
    for (int sl = 0; sl < 8; ++sl)
#pragma unroll
      for (int qq = 0; qq < 4; ++qq) {
        const float2 f =
            *(const float2*)&P[(s * 4 + qq) * 1024 + (sl * 64 + u) * 2];
        v[2 * qq] += f.x;
        v[2 * qq + 1] += f.y;
      }
  }
  const int row = (u >> 3) * 8 + s;
  const int ebase = (u & 7) * 8;
  const int gr = r0 + row;

  __syncthreads();  // P dead; stats region reusable
  float* PW = smem;                // [8][64] per-wave importance partials
  float* zw = smem + 512;          // [8] per-wave z2 partials
  int* cnt = (int*)(smem + 520);   // [64]
  if (t < 64) cnt[t] = 0;
  __syncthreads();

  // ---- per-row top-2 (lax.top_k ties: lower index wins) over 8 lanes ----
  float v1 = v[0]; int i1 = ebase;
  float v2 = -3.402823466e+38f; int i2 = 0;
#pragma unroll
  for (int q = 1; q < 8; ++q) {
    const float x = v[q];
    if (x > v1) { v2 = v1; i2 = i1; v1 = x; i1 = ebase + q; }
    else if (x > v2) { v2 = x; i2 = ebase + q; }
  }
#pragma unroll
  for (int m = 1; m <= 4; m <<= 1) {
    const float o1 = __shfl_xor(v1, m);
    const int oi1 = __shfl_xor(i1, m);
    const float o2 = __shfl_xor(v2, m);
    const int oi2 = __shfl_xor(i2, m);
    if (o1 > v1 || (o1 == v1 && oi1 < i1)) {
      const bool c2 = (o2 > v1) || (o2 == v1 && oi2 < i1);
      v2 = c2 ? o2 : v1; i2 = c2 ? oi2 : i1;
      v1 = o1; i1 = oi1;
    } else if (o1 > v2 || (o1 == v2 && oi1 < i2)) {
      v2 = o1; i2 = oi1;
    }
  }

  // ---- row softmax / z, fully in-register ----
  float p[8];
  float ssum = 0.f;
#pragma unroll
  for (int q = 0; q < 8; ++q) { p[q] = __expf(v[q] - v1); ssum += p[q]; }
#pragma unroll
  for (int m = 1; m <= 4; m <<= 1) ssum += __shfl_xor(ssum, m);
  const float rs = 1.f / ssum;
#pragma unroll
  for (int q = 0; q < 8; ++q) p[q] *= rs;

  {
    const float4 o0 = {p[0], p[1], p[2], p[3]};
    const float4 o1 = {p[4], p[5], p[6], p[7]};
    *(float4*)&out[OFF_PROBS + (size_t)gr * 64 + ebase] = o0;
    *(float4*)&out[OFF_PROBS + (size_t)gr * 64 + ebase + 4] = o1;
  }
  const float z = v1 + __logf(ssum);
  const float z2 = z * z;

  if ((u & 7) == 0) {  // one writer per row
    out[OFF_IDX + 2 * gr] = (float)i1;
    out[OFF_IDX + 2 * gr + 1] = (float)i2;
    const float e1 = __expf(v2 - v1);  // v2 <= v1, stable
    const float s0 = 1.f / (1.f + e1);
    out[OFF_SCORES + 2 * gr] = s0;
    out[OFF_SCORES + 2 * gr + 1] = e1 * s0;
    atomicAdd(&cnt[i1], 1);
    atomicAdd(&cnt[i2], 1);
  }

  // ---- per-wave stats: butterfly over lane bits 3..5 (the 8 row groups) ----
  float cs[8];
#pragma unroll
  for (int q = 0; q < 8; ++q) cs[q] = p[q];
#pragma unroll
  for (int m = 8; m <= 32; m <<= 1)
#pragma unroll
    for (int q = 0; q < 8; ++q) cs[q] += __shfl_xor(cs[q], m);
  float zs = z2;
#pragma unroll
  for (int m = 8; m <= 32; m <<= 1) zs += __shfl_xor(zs, m);
  if (u < 8) {
    const float4 c0 = {cs[0], cs[1], cs[2], cs[3]};
    const float4 c1 = {cs[4], cs[5], cs[6], cs[7]};
    *(float4*)&PW[s * 64 + u * 8] = c0;
    *(float4*)&PW[s * 64 + u * 8 + 4] = c1;
    if (u == 0) zw[s] = zs;
  }
  __syncthreads();

  // per-block stats -> ws (no global atomics; tiny reduce kernel finishes)
  if (t < 64) {
    float ic = 0.f;
#pragma unroll
    for (int w = 0; w < 8; ++w) ic += PW[w * 64 + t];
    ws[(size_t)blockIdx.x * WS_STRIDE + t] = ic;
    ws[(size_t)blockIdx.x * WS_STRIDE + 64 + t] = (float)cnt[t];
  } else if (t == 64) {
    float zz = 0.f;
#pragma unroll
    for (int w = 0; w < 8; ++w) zz += zw[w];
    ws[(size_t)blockIdx.x * WS_STRIDE + 128] = zz;
  }
}

// ---------------------------------------------------------------------------
// Final reduction over 256 per-block stat slots; 512 threads, 4-way k-split
// so loads pipeline instead of one serial 256-iteration loop per slot.
// ---------------------------------------------------------------------------
__global__ __launch_bounds__(512) void router_reduce(
    const float* __restrict__ ws, float* __restrict__ out) {
  __shared__ float part[4][128];
  __shared__ float zp[4];
  const int t = threadIdx.x;
  const int c = t >> 7;      // block-quarter 0..3
  const int slot = t & 127;  // 0..127 (64 imp | 64 cnt)
  float v = 0.f;
#pragma unroll 8
  for (int i = 0; i < 64; ++i)
    v += ws[(size_t)(c * 64 + i) * WS_STRIDE + slot];
  part[c][slot] = v;
  if (t < 4) {
    float zz = 0.f;
#pragma unroll 8
    for (int i = 0; i < 64; ++i)
      zz += ws[(size_t)(t * 64 + i) * WS_STRIDE + 128];
    zp[t] = zz;
  }
  __syncthreads();
  if (t < 128) {
    const float s4 = part[0][t] + part[1][t] + part[2][t] + part[3][t];
    if (t < 64)
      out[OFF_IMP + t] = s4 * (1.f / 16384.f);
    else
      // counts are integers; /32768 exact; denominator max(sum,1)=32768
      out[OFF_LOAD + (t - 64)] = s4 * (1.f / 32768.f);
  } else if (t == 128) {
    out[OFF_Z] = (zp[0] + zp[1] + zp[2] + zp[3]) * (1.f / 16384.f);
  }
}

extern "C" void kernel_launch(void* const* d_in, const int* in_sizes, int n_in,
                              void* d_out, int out_size, void* d_ws, size_t ws_size,
                              hipStream_t stream) {
  const float* x = (const float*)d_in[0];
  const float* wgate = (const float*)d_in[1];
  float* out = (float*)d_out;
  float* ws = (float*)d_ws;  // 256*132 floats, fully written each call

  router_fused<<<dim3(NBLK), dim3(512), 0, stream>>>(x, wgate, out, ws);
  router_reduce<<<dim3(1), dim3(512), 0, stream>>>(ws, out);
}

// Round 2
// 424.203 us; speedup vs baseline: 2.7159x; 2.7159x over previous
//
#include <hip/hip_runtime.h>

namespace {
constexpr int D = 4096;   // d_model
constexpr int E = 64;     // n_experts
constexpr int M = 16384;  // B*S
constexpr int BM = 64;    // rows per block
constexpr int BK = 128;   // k per round
constexpr int NT = D / BK;      // 32 rounds
constexpr int NBLK = M / BM;    // 256 blocks

// output layout (floats, concatenated in reference return order)
constexpr int OFF_IDX = 0;         // [M][2]
constexpr int OFF_SCORES = 32768;  // [M][2]
constexpr int OFF_PROBS = 65536;   // [M][64]
constexpr int OFF_Z = 1114112;     // scalar
constexpr int OFF_IMP = 1114113;   // [64]
constexpr int OFF_LOAD = 1114177;  // [64]

constexpr int WS_STRIDE = 132;  // per-block stats: 64 imp | 64 cnt | 1 z2
}  // namespace

// global->LDS direct DMA, 16 B per lane (dest = wave-uniform base + lane*16)
__device__ __forceinline__ void gload16(const float* g, float* l) {
  __builtin_amdgcn_global_load_lds(
      (const __attribute__((address_space(1))) void*)g,
      (__attribute__((address_space(3))) void*)l, 16, 0, 0);
}

// ---------------------------------------------------------------------------
// Fused router. 256 blocks x 512 threads (8 waves = 8 wave-aligned k-slices,
// 16 k each per round). LDS 128 KB double-buffered, granule-major:
//   granule g = 16B = (row, kc*4..kc*4+3); slot(row,kc) = row*32 + (kc ^ row>>3)
// Staging via global_load_lds with linear LDS dest; the swizzle is applied by
// permuting each lane's GLOBAL source address (LDS stays linear). Inner-loop
// ds_read_b128 per granule: 8 distinct bank-quads across ty/tx -> conflict-
// free, 8-way broadcast. 8x8 register tile; no staging VGPRs, no ds_writes.
// ---------------------------------------------------------------------------
__global__ __launch_bounds__(512, 1) void router_fused(
    const float* __restrict__ xg, const float* __restrict__ wg,
    float* __restrict__ out, float* __restrict__ ws) {
  __shared__ float smem[32768];  // 2 buffers x (X 8192 | W 8192 floats)

  const int t = threadIdx.x;
  const int u = t & 63;   // lane
  const int s = t >> 6;   // wave id = k-slice 0..7
  const int tx = u & 7;   // expert group (8 experts)
  const int ty = u >> 3;  // row group (8 rows)
  const int r0 = blockIdx.x * BM;

  // ---- staging roles: waves 0-3 stage X, waves 4-7 stage W ----
  // wave sw covers region slots [sw*512, sw*512+512), 8 calls x 64 granules.
  // slot -> row = slot>>5, kc = (slot&31) ^ (row>>3).
  const int sw = s & 3;
  const float* gbase = (s < 4) ? (xg + (size_t)r0 * D) : wg;
  const int rowA = sw * 16 + (u >> 5);       // calls 0..3: rows rowA+2c
  const int tyA = sw * 2;                    // row>>3 for calls 0..3
  const float* srcA = gbase + (size_t)rowA * D + (((u & 31) ^ tyA) << 2);
  const float* srcB =
      gbase + (size_t)(rowA + 8) * D + (((u & 31) ^ (tyA + 1)) << 2);
  const int dstoff = (s < 4 ? 0 : 8192) + sw * 2048;  // floats

  auto stage = [&](int r, float* buf) {
    const int rk = r * BK;  // k advance (floats) within each row
    float* dst = buf + dstoff;
#pragma unroll
    for (int c = 0; c < 4; ++c)
      gload16(srcA + rk + (size_t)(2 * c) * D, dst + c * 256);
#pragma unroll
    for (int c = 0; c < 4; ++c)
      gload16(srcB + rk + (size_t)(2 * c) * D, dst + 1024 + c * 256);
  };

  // ---- read offsets (floats): granule (ty*8+i, kc) at ty*1024+(kc^ty)*4+i*128
  int xoff[4], woff[4];
#pragma unroll
  for (int kr = 0; kr < 4; ++kr) {
    const int kc = s * 4 + kr;  // this slice's granule columns
    xoff[kr] = ty * 1024 + ((kc ^ ty) << 2);
    woff[kr] = 8192 + tx * 1024 + ((kc ^ tx) << 2);
  }

  float acc[8][8];
#pragma unroll
  for (int i = 0; i < 8; ++i)
#pragma unroll
    for (int j = 0; j < 8; ++j) acc[i][j] = 0.f;

  stage(0, smem);  // buffer 0

  for (int r = 0; r < NT; ++r) {
    __syncthreads();  // tile r staged (compiler drains vmcnt before barrier)
    if (r + 1 < NT) stage(r + 1, smem + ((r + 1) & 1) * 16384);

    const float* buf = smem + (r & 1) * 16384;
#pragma unroll
    for (int kr = 0; kr < 4; ++kr) {
      float4 bw[8];
#pragma unroll
      for (int j = 0; j < 8; ++j)
        bw[j] = *(const float4*)&buf[woff[kr] + j * 128];
#pragma unroll
      for (int i = 0; i < 8; ++i) {
        const float4 ax = *(const float4*)&buf[xoff[kr] + i * 128];
#pragma unroll
        for (int j = 0; j < 8; ++j) {
          acc[i][j] = fmaf(ax.x, bw[j].x, acc[i][j]);
          acc[i][j] = fmaf(ax.y, bw[j].y, acc[i][j]);
          acc[i][j] = fmaf(ax.z, bw[j].z, acc[i][j]);
          acc[i][j] = fmaf(ax.w, bw[j].w, acc[i][j]);
        }
      }
    }
  }

  // ---- cross-slice reduction, distributed over all 512 threads ----
  // P[jp][slice*64+u][2] float2 layout: both sides bank-optimal.
  // acc[i][j] of thread (s,u) is logits(row=(u>>3)*8+i, e=(u&7)*8+j).
  __syncthreads();  // all compute done; gemm buffers reusable
  {
    float* P = smem;
    const int su2 = (s * 64 + u) * 2;
#pragma unroll
    for (int i = 0; i < 8; ++i)
#pragma unroll
      for (int jj = 0; jj < 4; ++jj)
        *(float2*)&P[(i * 4 + jj) * 1024 + su2] =
            make_float2(acc[i][2 * jj], acc[i][2 * jj + 1]);
  }
  __syncthreads();

  // thread t = (s,u) gathers row (u>>3)*8 + s, experts (u&7)*8 + 0..7
  float v[8];
#pragma unroll
  for (int q = 0; q < 8; ++q) v[q] = 0.f;
  {
    const float* P = smem;
#pragma unroll
    for (int sl = 0; sl < 8; ++sl)
#pragma unroll
      for (int qq = 0; qq < 4; ++qq) {
        const float2 f =
            *(const float2*)&P[(s * 4 + qq) * 1024 + (sl * 64 + u) * 2];
        v[2 * qq] += f.x;
        v[2 * qq + 1] += f.y;
      }
  }
  const int row = (u >> 3) * 8 + s;
  const int ebase = (u & 7) * 8;
  const int gr = r0 + row;

  __syncthreads();  // P dead; stats region reusable
  float* PW = smem;                // [8][64] per-wave importance partials
  float* zw = smem + 512;          // [8] per-wave z2 partials
  int* cnt = (int*)(smem + 520);   // [64]
  if (t < 64) cnt[t] = 0;
  __syncthreads();

  // ---- per-row top-2 (lax.top_k ties: lower index wins) over 8 lanes ----
  float v1 = v[0]; int i1 = ebase;
  float v2 = -3.402823466e+38f; int i2 = 0;
#pragma unroll
  for (int q = 1; q < 8; ++q) {
    const float x = v[q];
    if (x > v1) { v2 = v1; i2 = i1; v1 = x; i1 = ebase + q; }
    else if (x > v2) { v2 = x; i2 = ebase + q; }
  }
#pragma unroll
  for (int m = 1; m <= 4; m <<= 1) {
    const float o1 = __shfl_xor(v1, m);
    const int oi1 = __shfl_xor(i1, m);
    const float o2 = __shfl_xor(v2, m);
    const int oi2 = __shfl_xor(i2, m);
    if (o1 > v1 || (o1 == v1 && oi1 < i1)) {
      const bool c2 = (o2 > v1) || (o2 == v1 && oi2 < i1);
      v2 = c2 ? o2 : v1; i2 = c2 ? oi2 : i1;
      v1 = o1; i1 = oi1;
    } else if (o1 > v2 || (o1 == v2 && oi1 < i2)) {
      v2 = o1; i2 = oi1;
    }
  }

  // ---- row softmax / z, fully in-register ----
  float p[8];
  float ssum = 0.f;
#pragma unroll
  for (int q = 0; q < 8; ++q) { p[q] = __expf(v[q] - v1); ssum += p[q]; }
#pragma unroll
  for (int m = 1; m <= 4; m <<= 1) ssum += __shfl_xor(ssum, m);
  const float rs = 1.f / ssum;
#pragma unroll
  for (int q = 0; q < 8; ++q) p[q] *= rs;

  {
    const float4 o0 = {p[0], p[1], p[2], p[3]};
    const float4 o1 = {p[4], p[5], p[6], p[7]};
    *(float4*)&out[OFF_PROBS + (size_t)gr * 64 + ebase] = o0;
    *(float4*)&out[OFF_PROBS + (size_t)gr * 64 + ebase + 4] = o1;
  }
  const float z = v1 + __logf(ssum);
  const float z2 = z * z;

  if ((u & 7) == 0) {  // one writer per row
    out[OFF_IDX + 2 * gr] = (float)i1;
    out[OFF_IDX + 2 * gr + 1] = (float)i2;
    const float e1 = __expf(v2 - v1);  // v2 <= v1, stable
    const float s0 = 1.f / (1.f + e1);
    out[OFF_SCORES + 2 * gr] = s0;
    out[OFF_SCORES + 2 * gr + 1] = e1 * s0;
    atomicAdd(&cnt[i1], 1);
    atomicAdd(&cnt[i2], 1);
  }

  // ---- per-wave stats: butterfly over lane bits 3..5 (the 8 row groups) ----
  float cs[8];
#pragma unroll
  for (int q = 0; q < 8; ++q) cs[q] = p[q];
#pragma unroll
  for (int m = 8; m <= 32; m <<= 1)
#pragma unroll
    for (int q = 0; q < 8; ++q) cs[q] += __shfl_xor(cs[q], m);
  float zs = z2;
#pragma unroll
  for (int m = 8; m <= 32; m <<= 1) zs += __shfl_xor(zs, m);
  if (u < 8) {
    const float4 c0 = {cs[0], cs[1], cs[2], cs[3]};
    const float4 c1 = {cs[4], cs[5], cs[6], cs[7]};
    *(float4*)&PW[s * 64 + u * 8] = c0;
    *(float4*)&PW[s * 64 + u * 8 + 4] = c1;
    if (u == 0) zw[s] = zs;
  }
  __syncthreads();

  // per-block stats -> ws (no global atomics; tiny reduce kernel finishes)
  if (t < 64) {
    float ic = 0.f;
#pragma unroll
    for (int w = 0; w < 8; ++w) ic += PW[w * 64 + t];
    ws[(size_t)blockIdx.x * WS_STRIDE + t] = ic;
    ws[(size_t)blockIdx.x * WS_STRIDE + 64 + t] = (float)cnt[t];
  } else if (t == 64) {
    float zz = 0.f;
#pragma unroll
    for (int w = 0; w < 8; ++w) zz += zw[w];
    ws[(size_t)blockIdx.x * WS_STRIDE + 128] = zz;
  }
}

// ---------------------------------------------------------------------------
// Final reduction over 256 per-block stat slots; 512 threads, 4-way k-split.
// ---------------------------------------------------------------------------
__global__ __launch_bounds__(512) void router_reduce(
    const float* __restrict__ ws, float* __restrict__ out) {
  __shared__ float part[4][128];
  __shared__ float zp[4];
  const int t = threadIdx.x;
  const int c = t >> 7;      // block-quarter 0..3
  const int slot = t & 127;  // 0..127 (64 imp | 64 cnt)
  float v = 0.f;
#pragma unroll 8
  for (int i = 0; i < 64; ++i)
    v += ws[(size_t)(c * 64 + i) * WS_STRIDE + slot];
  part[c][slot] = v;
  if (t < 4) {
    float zz = 0.f;
#pragma unroll 8
    for (int i = 0; i < 64; ++i)
      zz += ws[(size_t)(t * 64 + i) * WS_STRIDE + 128];
    zp[t] = zz;
  }
  __syncthreads();
  if (t < 128) {
    const float s4 = part[0][t] + part[1][t] + part[2][t] + part[3][t];
    if (t < 64)
      out[OFF_IMP + t] = s4 * (1.f / 16384.f);
    else
      // counts are integers; /32768 exact; denominator max(sum,1)=32768
      out[OFF_LOAD + (t - 64)] = s4 * (1.f / 32768.f);
  } else if (t == 128) {
    out[OFF_Z] = (zp[0] + zp[1] + zp[2] + zp[3]) * (1.f / 16384.f);
  }
}

extern "C" void kernel_launch(void* const* d_in, const int* in_sizes, int n_in,
                              void* d_out, int out_size, void* d_ws, size_t ws_size,
                              hipStream_t stream) {
  const float* x = (const float*)d_in[0];
  const float* wgate = (const float*)d_in[1];
  float* out = (float*)d_out;
  float* ws = (float*)d_ws;  // 256*132 floats, fully written each call

  router_fused<<<dim3(NBLK), dim3(512), 0, stream>>>(x, wgate, out, ws);
  router_reduce<<<dim3(1), dim3(512), 0, stream>>>(ws, out);
}